// Round 2
// baseline (3244.730 us; speedup 1.0000x reference)
//
#include <hip/hip_runtime.h>
#include <math.h>

#define N_NODES 50000
#define N_EDGES 800000
#define DIM 128
#define TILE 32
#define LN_EPS 1e-5f

// H (edge): [32][384] padded stride 388 floats
#define ESTRIDE 388
// H (node): [32][256] padded stride 260
#define NSTRIDE 260
// hidden H1/H2: [32][128] padded stride 132
#define HSTRIDE 132

__device__ __forceinline__ float silu_f(float v) {
    return v / (1.0f + expf(-v));
}

__device__ __forceinline__ int clamp_idx(int v) {
    v = v < 0 ? 0 : v;
    return v >= N_NODES ? N_NODES - 1 : v;
}

// Computes a [4 rows x 4 cols] tile of  H(lds, stride LSTR, K cols) @ W[K][128] + b.
// Thread t: rb = t>>5 owns rows 4*rb..4*rb+3, cb = t&31 owns cols 4*cb..4*cb+3.
template<int K, int LSTR>
__device__ __forceinline__ void gemm_tile(const float* lds,
                                          const float* __restrict__ W,
                                          const float* __restrict__ b,
                                          int rb, int cb, float acc[4][4]) {
    const int c0 = cb * 4;
    const float4 bv = *(const float4*)(b + c0);
#pragma unroll
    for (int r = 0; r < 4; ++r) {
        acc[r][0] = bv.x; acc[r][1] = bv.y; acc[r][2] = bv.z; acc[r][3] = bv.w;
    }
    const float* hp = lds + (rb * 4) * LSTR;
    const float4* wp = (const float4*)(W + c0);
#pragma unroll 4
    for (int k = 0; k < K; ++k) {
        const float4 w = wp[k * 32];              // W[k][c0..c0+3], L1-broadcast
#pragma unroll
        for (int r = 0; r < 4; ++r) {
            const float h = hp[r * LSTR + k];     // LDS broadcast (2 addrs/wave)
            acc[r][0] = fmaf(h, w.x, acc[r][0]);
            acc[r][1] = fmaf(h, w.y, acc[r][1]);
            acc[r][2] = fmaf(h, w.z, acc[r][2]);
            acc[r][3] = fmaf(h, w.w, acc[r][3]);
        }
    }
}

// Each row's 128 cols are spread over 32 lanes (4 each); rb is fixed per
// half-wave. Reduce sum + sumsq across the 32-lane half, then normalize.
__device__ __forceinline__ void layernorm_tile(float acc[4][4],
                                               const float* __restrict__ g,
                                               const float* __restrict__ bt,
                                               int cb) {
    const int c0 = cb * 4;
    float s[4], q[4];
#pragma unroll
    for (int r = 0; r < 4; ++r) {
        s[r] = acc[r][0] + acc[r][1] + acc[r][2] + acc[r][3];
        q[r] = acc[r][0]*acc[r][0] + acc[r][1]*acc[r][1]
             + acc[r][2]*acc[r][2] + acc[r][3]*acc[r][3];
    }
#pragma unroll
    for (int m = 1; m < 32; m <<= 1) {
#pragma unroll
        for (int r = 0; r < 4; ++r) {
            s[r] += __shfl_xor(s[r], m);
            q[r] += __shfl_xor(q[r], m);
        }
    }
    const float4 gv = *(const float4*)(g + c0);
    const float4 bv = *(const float4*)(bt + c0);
    const float gg[4] = {gv.x, gv.y, gv.z, gv.w};
    const float bb[4] = {bv.x, bv.y, bv.z, bv.w};
#pragma unroll
    for (int r = 0; r < 4; ++r) {
        const float mu = s[r] * (1.0f / 128.0f);
        float var = q[r] * (1.0f / 128.0f) - mu * mu;
        const float rstd = rsqrtf(var + LN_EPS);
#pragma unroll
        for (int c = 0; c < 4; ++c)
            acc[r][c] = (acc[r][c] - mu) * rstd * gg[c] + bb[c];
    }
}

__global__ __launch_bounds__(256)
void edge_kernel(const float* __restrict__ x, const int* __restrict__ ei,
                 const float* __restrict__ ea,
                 const float* __restrict__ W1, const float* __restrict__ b1,
                 const float* __restrict__ W2, const float* __restrict__ b2,
                 const float* __restrict__ W3, const float* __restrict__ b3,
                 const float* __restrict__ g,  const float* __restrict__ bt,
                 float* __restrict__ out_e, float* __restrict__ agg) {
    __shared__ float lds[TILE * ESTRIDE];
    __shared__ int idx_i[TILE], idx_j[TILE];
    const int t = threadIdx.x;
    const int e0 = blockIdx.x * TILE;

    if (t < TILE)            idx_i[t] = clamp_idx(ei[e0 + t]);
    else if (t < 2 * TILE)   idx_j[t - TILE] = clamp_idx(ei[N_EDGES + e0 + (t - TILE)]);
    __syncthreads();

    // Gather concat([x[i], x[j], ea[e]]) -> lds[row][0..383], 3072 float4 total.
#pragma unroll
    for (int it = 0; it < 12; ++it) {
        const int qn = it * 256 + t;       // 0..3071
        const int row = qn / 96;
        const int p = qn - row * 96;
        const int seg = p >> 5;            // 0,1,2
        const int c4 = p & 31;
        const float* src;
        if (seg == 0)      src = x + (size_t)idx_i[row] * DIM;
        else if (seg == 1) src = x + (size_t)idx_j[row] * DIM;
        else               src = ea + (size_t)(e0 + row) * DIM;
        const float4 v = *(const float4*)(src + c4 * 4);
        *(float4*)&lds[row * ESTRIDE + seg * 128 + c4 * 4] = v;
    }
    __syncthreads();

    const int rb = t >> 5, cb = t & 31;
    const int c0 = cb * 4;
    float acc[4][4];

    gemm_tile<384, ESTRIDE>(lds, W1, b1, rb, cb, acc);
#pragma unroll
    for (int r = 0; r < 4; ++r)
#pragma unroll
        for (int c = 0; c < 4; ++c) acc[r][c] = silu_f(acc[r][c]);
    __syncthreads();
#pragma unroll
    for (int r = 0; r < 4; ++r)
        *(float4*)&lds[(rb * 4 + r) * HSTRIDE + c0] =
            make_float4(acc[r][0], acc[r][1], acc[r][2], acc[r][3]);
    __syncthreads();

    gemm_tile<128, HSTRIDE>(lds, W2, b2, rb, cb, acc);
#pragma unroll
    for (int r = 0; r < 4; ++r)
#pragma unroll
        for (int c = 0; c < 4; ++c) acc[r][c] = silu_f(acc[r][c]);
    __syncthreads();
#pragma unroll
    for (int r = 0; r < 4; ++r)
        *(float4*)&lds[(rb * 4 + r) * HSTRIDE + c0] =
            make_float4(acc[r][0], acc[r][1], acc[r][2], acc[r][3]);
    __syncthreads();

    gemm_tile<128, HSTRIDE>(lds, W3, b3, rb, cb, acc);
    layernorm_tile(acc, g, bt, cb);

    // residual + store + scatter
#pragma unroll
    for (int r = 0; r < 4; ++r) {
        const int e = e0 + rb * 4 + r;
        const float4 res = *(const float4*)(ea + (size_t)e * DIM + c0);
        float4 o = make_float4(acc[r][0] + res.x, acc[r][1] + res.y,
                               acc[r][2] + res.z, acc[r][3] + res.w);
        *(float4*)(out_e + (size_t)e * DIM + c0) = o;
        float* ag = agg + (size_t)idx_j[rb * 4 + r] * DIM + c0;
        atomicAdd(ag + 0, o.x);
        atomicAdd(ag + 1, o.y);
        atomicAdd(ag + 2, o.z);
        atomicAdd(ag + 3, o.w);
    }
}

__global__ __launch_bounds__(256)
void node_kernel(const float* __restrict__ x, const float* __restrict__ agg,
                 const float* __restrict__ W1, const float* __restrict__ b1,
                 const float* __restrict__ W2, const float* __restrict__ b2,
                 const float* __restrict__ W3, const float* __restrict__ b3,
                 const float* __restrict__ g,  const float* __restrict__ bt,
                 float* __restrict__ out_x) {
    __shared__ float lds[TILE * NSTRIDE];
    const int t = threadIdx.x;
    const int v0 = blockIdx.x * TILE;

    // Gather concat([x[v], agg[v]]) -> lds[row][0..255], 2048 float4.
#pragma unroll
    for (int it = 0; it < 8; ++it) {
        const int qn = it * 256 + t;       // 0..2047
        const int row = qn >> 6;
        const int p = qn & 63;
        const int seg = p >> 5;
        const int c4 = p & 31;
        if (v0 + row < N_NODES) {
            const float* src = (seg == 0) ? x + (size_t)(v0 + row) * DIM
                                          : agg + (size_t)(v0 + row) * DIM;
            const float4 v = *(const float4*)(src + c4 * 4);
            *(float4*)&lds[row * NSTRIDE + seg * 128 + c4 * 4] = v;
        }
    }
    __syncthreads();

    const int rb = t >> 5, cb = t & 31;
    const int c0 = cb * 4;
    float acc[4][4];

    gemm_tile<256, NSTRIDE>(lds, W1, b1, rb, cb, acc);
#pragma unroll
    for (int r = 0; r < 4; ++r)
#pragma unroll
        for (int c = 0; c < 4; ++c) acc[r][c] = silu_f(acc[r][c]);
    __syncthreads();
#pragma unroll
    for (int r = 0; r < 4; ++r)
        *(float4*)&lds[(rb * 4 + r) * HSTRIDE + c0] =
            make_float4(acc[r][0], acc[r][1], acc[r][2], acc[r][3]);
    __syncthreads();

    gemm_tile<128, HSTRIDE>(lds, W2, b2, rb, cb, acc);
#pragma unroll
    for (int r = 0; r < 4; ++r)
#pragma unroll
        for (int c = 0; c < 4; ++c) acc[r][c] = silu_f(acc[r][c]);
    __syncthreads();
#pragma unroll
    for (int r = 0; r < 4; ++r)
        *(float4*)&lds[(rb * 4 + r) * HSTRIDE + c0] =
            make_float4(acc[r][0], acc[r][1], acc[r][2], acc[r][3]);
    __syncthreads();

    gemm_tile<128, HSTRIDE>(lds, W3, b3, rb, cb, acc);
    layernorm_tile(acc, g, bt, cb);

#pragma unroll
    for (int r = 0; r < 4; ++r) {
        const int v = v0 + rb * 4 + r;
        if (v < N_NODES) {
            const float4 res = *(const float4*)(x + (size_t)v * DIM + c0);
            float4 o = make_float4(acc[r][0] + res.x, acc[r][1] + res.y,
                                   acc[r][2] + res.z, acc[r][3] + res.w);
            *(float4*)(out_x + (size_t)v * DIM + c0) = o;
        }
    }
}

extern "C" void kernel_launch(void* const* d_in, const int* in_sizes, int n_in,
                              void* d_out, int out_size, void* d_ws, size_t ws_size,
                              hipStream_t stream) {
    const float* x   = (const float*)d_in[0];
    const int*   ei  = (const int*)d_in[1];
    const float* ea  = (const float*)d_in[2];
    const float* ew1 = (const float*)d_in[3];
    const float* eb1 = (const float*)d_in[4];
    const float* ew2 = (const float*)d_in[5];
    const float* eb2 = (const float*)d_in[6];
    const float* ew3 = (const float*)d_in[7];
    const float* eb3 = (const float*)d_in[8];
    const float* eg  = (const float*)d_in[9];
    const float* ebt = (const float*)d_in[10];
    const float* nw1 = (const float*)d_in[11];
    const float* nb1 = (const float*)d_in[12];
    const float* nw2 = (const float*)d_in[13];
    const float* nb2 = (const float*)d_in[14];
    const float* nw3 = (const float*)d_in[15];
    const float* nb3 = (const float*)d_in[16];
    const float* ng  = (const float*)d_in[17];
    const float* nbt = (const float*)d_in[18];

    float* out_x = (float*)d_out;                       // [N_NODES,128]
    float* out_e = out_x + (size_t)N_NODES * DIM;       // [N_EDGES,128]
    float* agg   = (float*)d_ws;                        // [N_NODES,128]

    hipMemsetAsync(agg, 0, (size_t)N_NODES * DIM * sizeof(float), stream);

    edge_kernel<<<N_EDGES / TILE, 256, 0, stream>>>(
        x, ei, ea, ew1, eb1, ew2, eb2, ew3, eb3, eg, ebt, out_e, agg);

    node_kernel<<<(N_NODES + TILE - 1) / TILE, 256, 0, stream>>>(
        x, agg, nw1, nb1, nw2, nb2, nw3, nb3, ng, nbt, out_x);
}

// Round 3
// 1536.080 us; speedup vs baseline: 2.1123x; 2.1123x over previous
//
#include <hip/hip_runtime.h>
#include <math.h>
#include <stdint.h>

#define N_NODES 50000
#define N_EDGES 800000
#define DIM 128
#define LN_EPS 1e-5f

typedef __bf16 bf16x8 __attribute__((ext_vector_type(8)));
typedef float f32x4 __attribute__((ext_vector_type(4)));

union FragU { uint32_t u[4]; bf16x8 v; };

__device__ __forceinline__ int clampi(int v) {
    v = v < 0 ? 0 : v; return v >= N_NODES ? N_NODES - 1 : v;
}

__device__ __forceinline__ void gl_lds16(const void* g, void* l) {
    __builtin_amdgcn_global_load_lds(
        (const __attribute__((address_space(1))) void*)g,
        (__attribute__((address_space(3))) void*)l, 16, 0, 0);
}

__device__ __forceinline__ f32x4 mfma16(bf16x8 a, bf16x8 b, f32x4 c) {
    return __builtin_amdgcn_mfma_f32_16x16x32_bf16(a, b, c, 0, 0, 0);
}

// Stage one 64-row x 128-col fp32 segment into A_lds.
// LDS slot granule s (16B) of row r holds source granule s ^ (r & 15).
template<class F>
__device__ __forceinline__ void stage_A(float* A_lds, int wave, int lane, F src_of_row) {
#pragma unroll
    for (int j = 0; j < 8; ++j) {
        const int G = wave * 512 + j * 64 + lane;     // dest granule
        const int row = G >> 5;
        const int gr = G & 31;
        const int c = gr ^ (row & 15);                // source granule
        gl_lds16(src_of_row(row) + c * 4, &A_lds[(wave * 512 + j * 64) * 4]);
    }
}

// Stage one 16KB weight slab (prep layout == LDS layout, identity copy).
__device__ __forceinline__ void stage_B(unsigned short* Bdst,
                                        const unsigned short* Wslab,
                                        int wave, int lane) {
#pragma unroll
    for (int j = 0; j < 4; ++j) {
        const int G = wave * 256 + j * 64 + lane;
        gl_lds16(Wslab + (size_t)G * 8, Bdst + (wave * 256 + j * 64) * 8);
    }
}

__device__ __forceinline__ void init_acc(f32x4 acc[2][4], const float* __restrict__ b,
                                         int wn, int lc) {
#pragma unroll
    for (int nf = 0; nf < 4; ++nf) {
        const float bv = b[wn * 64 + nf * 16 + lc];
#pragma unroll
        for (int mf = 0; mf < 2; ++mf) acc[mf][nf] = (f32x4){bv, bv, bv, bv};
    }
}

// One K=32 MFMA step: split-fp32 A (from swizzled fp32 LDS) x prepped bf16 B slab.
__device__ __forceinline__ void compute_step(const float* A_lds,
                                             const unsigned short* B_lds,
                                             int ks, int wm, int wn, int lane,
                                             f32x4 acc[2][4]) {
    const int lc = lane & 15, lq = lane >> 4;
    FragU Ah[2], Al[2];
#pragma unroll
    for (int mf = 0; mf < 2; ++mf) {
        const int row = wm * 32 + mf * 16 + lc;
        const int g0 = ks * 8 + lq * 2;
        const f32x4 a = *(const f32x4*)&A_lds[row * 128 + ((g0 ^ (row & 15)) << 2)];
        const f32x4 b = *(const f32x4*)&A_lds[row * 128 + (((g0 + 1) ^ (row & 15)) << 2)];
        const float vv[8] = {a[0], a[1], a[2], a[3], b[0], b[1], b[2], b[3]};
#pragma unroll
        for (int p = 0; p < 4; ++p) {
            const uint32_t h0 = __float_as_uint(vv[2 * p])     & 0xFFFF0000u;
            const uint32_t h1 = __float_as_uint(vv[2 * p + 1]) & 0xFFFF0000u;
            const float r0 = vv[2 * p]     - __uint_as_float(h0);
            const float r1 = vv[2 * p + 1] - __uint_as_float(h1);
            Ah[mf].u[p] = (h0 >> 16) | h1;
            Al[mf].u[p] = (__float_as_uint(r0) >> 16) | (__float_as_uint(r1) & 0xFFFF0000u);
        }
    }
#pragma unroll
    for (int nf = 0; nf < 4; ++nf) {
        const int n = wn * 64 + nf * 16 + lc;
        FragU Bh, Bl;
        Bh.v = *(const bf16x8*)&B_lds[(lq * 128 + n) * 8];
        Bl.v = *(const bf16x8*)&B_lds[4096 + (lq * 128 + n) * 8];
#pragma unroll
        for (int mf = 0; mf < 2; ++mf) {
            acc[mf][nf] = mfma16(Ah[mf].v, Bh.v, acc[mf][nf]);
            acc[mf][nf] = mfma16(Al[mf].v, Bh.v, acc[mf][nf]);
            acc[mf][nf] = mfma16(Ah[mf].v, Bl.v, acc[mf][nf]);
        }
    }
}

// SiLU (optional) + write acc back into A_lds (swizzled fp32) as next GEMM input.
__device__ __forceinline__ void write_H(float* A_lds, int wm, int wn, int lane,
                                        f32x4 acc[2][4], bool do_silu) {
    const int lc = lane & 15, lq = lane >> 4;
#pragma unroll
    for (int mf = 0; mf < 2; ++mf)
#pragma unroll
        for (int nf = 0; nf < 4; ++nf)
#pragma unroll
            for (int r = 0; r < 4; ++r) {
                const int row = wm * 32 + mf * 16 + lq * 4 + r;
                const int col = wn * 64 + nf * 16 + lc;
                float v = acc[mf][nf][r];
                if (do_silu) v = v / (1.0f + __expf(-v));
                A_lds[row * 128 + (((col >> 2) ^ (row & 15)) << 2) + (col & 3)] = v;
            }
}

// Weight prep: fp32 W[K][128] -> per-32k slab layout [slab][hi/lo][kq][n][e] bf16.
__global__ __launch_bounds__(256)
void prep_w(const float* __restrict__ W, unsigned short* __restrict__ out) {
    const int slab = blockIdx.x;
    const int t = threadIdx.x;
#pragma unroll
    for (int vv = 0; vv < 16; ++vv) {
        const int o = vv * 256 + t;                  // 0..4095 within plane
        const int q = o >> 10, n = (o >> 3) & 127, e = o & 7;
        const int k = slab * 32 + q * 8 + e;
        const float f = W[(size_t)k * DIM + n];
        const uint32_t hb = __float_as_uint(f) & 0xFFFF0000u;
        const float r = f - __uint_as_float(hb);
        out[(size_t)slab * 8192 + o] = (unsigned short)(hb >> 16);
        out[(size_t)slab * 8192 + 4096 + o] = (unsigned short)(__float_as_uint(r) >> 16);
    }
}

__global__ __launch_bounds__(256, 2)
void edge_mfma(const float* __restrict__ x, const int* __restrict__ ei,
               const float* __restrict__ ea,
               const unsigned short* __restrict__ W1p, const float* __restrict__ b1,
               const unsigned short* __restrict__ W2p, const float* __restrict__ b2,
               const unsigned short* __restrict__ W3p, const float* __restrict__ b3,
               const float* __restrict__ g, const float* __restrict__ bt,
               float* __restrict__ out_e, float* __restrict__ agg) {
    __shared__ __align__(16) float A_lds[64 * 128];
    __shared__ __align__(16) unsigned short B_lds[2][8192];
    __shared__ int idxi[64], idxj[64];
    __shared__ float red[2][64][2];

    const int t = threadIdx.x;
    const int wave = t >> 6, lane = t & 63;
    const int wm = wave & 1, wn = wave >> 1;
    const int lc = lane & 15, lq = lane >> 4;
    const int e0 = blockIdx.x * 64;

    if (t < 64) idxi[t] = clampi(ei[e0 + t]);
    else if (t < 128) idxj[t - 64] = clampi(ei[N_EDGES + e0 + t - 64]);
    __syncthreads();

    stage_A(A_lds, wave, lane, [&](int row) { return x + (size_t)idxi[row] * DIM; });
    stage_B(B_lds[0], W1p, wave, lane);
    __syncthreads();

    f32x4 acc[2][4];
    init_acc(acc, b1, wn, lc);

    // GEMM1: K=384 (segs: x[i], x[j], ea), 12 slabs
    for (int s = 0; s < 12; ++s) {
        stage_B(B_lds[(s + 1) & 1], s < 11 ? W1p + (size_t)(s + 1) * 8192 : W2p, wave, lane);
        compute_step(A_lds, B_lds[s & 1], s & 3, wm, wn, lane, acc);
        __syncthreads();
        if (s == 3) {
            stage_A(A_lds, wave, lane, [&](int row) { return x + (size_t)idxj[row] * DIM; });
            __syncthreads();
        } else if (s == 7) {
            stage_A(A_lds, wave, lane, [&](int row) { return ea + (size_t)(e0 + row) * DIM; });
            __syncthreads();
        }
    }
    write_H(A_lds, wm, wn, lane, acc, true);
    __syncthreads();

    // GEMM2: K=128, 4 slabs (global parity continues: slab 12+s -> buf s&1)
    init_acc(acc, b2, wn, lc);
    for (int s = 0; s < 4; ++s) {
        stage_B(B_lds[(s + 1) & 1], s < 3 ? W2p + (size_t)(s + 1) * 8192 : W3p, wave, lane);
        compute_step(A_lds, B_lds[s & 1], s, wm, wn, lane, acc);
        __syncthreads();
    }
    write_H(A_lds, wm, wn, lane, acc, true);
    __syncthreads();

    // GEMM3: K=128
    init_acc(acc, b3, wn, lc);
    for (int s = 0; s < 4; ++s) {
        if (s < 3) stage_B(B_lds[(s + 1) & 1], W3p + (size_t)(s + 1) * 8192, wave, lane);
        compute_step(A_lds, B_lds[s & 1], s, wm, wn, lane, acc);
        if (s < 3) __syncthreads();
    }

    // LayerNorm: row sums over this wave's 64-col half, then cross-wave via LDS.
    {
        float s_[2][4], q_[2][4];
#pragma unroll
        for (int mf = 0; mf < 2; ++mf)
#pragma unroll
            for (int r = 0; r < 4; ++r) {
                float s = 0.f, qq = 0.f;
#pragma unroll
                for (int nf = 0; nf < 4; ++nf) {
                    const float v = acc[mf][nf][r];
                    s += v; qq += v * v;
                }
                s_[mf][r] = s; q_[mf][r] = qq;
            }
#pragma unroll
        for (int m = 1; m < 16; m <<= 1)
#pragma unroll
            for (int mf = 0; mf < 2; ++mf)
#pragma unroll
                for (int r = 0; r < 4; ++r) {
                    s_[mf][r] += __shfl_xor(s_[mf][r], m, 64);
                    q_[mf][r] += __shfl_xor(q_[mf][r], m, 64);
                }
        if (lc == 0) {
#pragma unroll
            for (int mf = 0; mf < 2; ++mf)
#pragma unroll
                for (int r = 0; r < 4; ++r) {
                    const int row = wm * 32 + mf * 16 + lq * 4 + r;
                    red[wn][row][0] = s_[mf][r];
                    red[wn][row][1] = q_[mf][r];
                }
        }
    }
    __syncthreads();

    float mu[2][4], rs[2][4];
#pragma unroll
    for (int mf = 0; mf < 2; ++mf)
#pragma unroll
        for (int r = 0; r < 4; ++r) {
            const int row = wm * 32 + mf * 16 + lq * 4 + r;
            const float S = red[0][row][0] + red[1][row][0];
            const float Q = red[0][row][1] + red[1][row][1];
            const float m_ = S * (1.0f / 128.0f);
            mu[mf][r] = m_;
            rs[mf][r] = rsqrtf(Q * (1.0f / 128.0f) - m_ * m_ + LN_EPS);
        }

#pragma unroll
    for (int nf = 0; nf < 4; ++nf) {
        const int col = wn * 64 + nf * 16 + lc;
        const float gc = g[col], bc = bt[col];
#pragma unroll
        for (int mf = 0; mf < 2; ++mf)
#pragma unroll
            for (int r = 0; r < 4; ++r) {
                const int row = wm * 32 + mf * 16 + lq * 4 + r;
                const int e = e0 + row;
                float o = (acc[mf][nf][r] - mu[mf][r]) * rs[mf][r] * gc + bc;
                o += ea[(size_t)e * DIM + col];
                out_e[(size_t)e * DIM + col] = o;
                atomicAdd(&agg[(size_t)idxj[row] * DIM + col], o);
            }
    }
}

__global__ __launch_bounds__(256, 2)
void node_mfma(const float* __restrict__ x, const float* __restrict__ agg,
               const unsigned short* __restrict__ W1p, const float* __restrict__ b1,
               const unsigned short* __restrict__ W2p, const float* __restrict__ b2,
               const unsigned short* __restrict__ W3p, const float* __restrict__ b3,
               const float* __restrict__ g, const float* __restrict__ bt,
               float* __restrict__ out_x) {
    __shared__ __align__(16) float A_lds[64 * 128];
    __shared__ __align__(16) unsigned short B_lds[2][8192];
    __shared__ float red[2][64][2];

    const int t = threadIdx.x;
    const int wave = t >> 6, lane = t & 63;
    const int wm = wave & 1, wn = wave >> 1;
    const int lc = lane & 15, lq = lane >> 4;
    const int v0 = blockIdx.x * 64;

    stage_A(A_lds, wave, lane, [&](int row) {
        int nidx = v0 + row; nidx = nidx < N_NODES ? nidx : N_NODES - 1;
        return x + (size_t)nidx * DIM;
    });
    stage_B(B_lds[0], W1p, wave, lane);
    __syncthreads();

    f32x4 acc[2][4];
    init_acc(acc, b1, wn, lc);

    // GEMM1: K=256 (segs: x, agg), 8 slabs
    for (int s = 0; s < 8; ++s) {
        stage_B(B_lds[(s + 1) & 1], s < 7 ? W1p + (size_t)(s + 1) * 8192 : W2p, wave, lane);
        compute_step(A_lds, B_lds[s & 1], s & 3, wm, wn, lane, acc);
        __syncthreads();
        if (s == 3) {
            stage_A(A_lds, wave, lane, [&](int row) {
                int nidx = v0 + row; nidx = nidx < N_NODES ? nidx : N_NODES - 1;
                return agg + (size_t)nidx * DIM;
            });
            __syncthreads();
        }
    }
    write_H(A_lds, wm, wn, lane, acc, true);
    __syncthreads();

    init_acc(acc, b2, wn, lc);
    for (int s = 0; s < 4; ++s) {
        stage_B(B_lds[(s + 1) & 1], s < 3 ? W2p + (size_t)(s + 1) * 8192 : W3p, wave, lane);
        compute_step(A_lds, B_lds[s & 1], s, wm, wn, lane, acc);
        __syncthreads();
    }
    write_H(A_lds, wm, wn, lane, acc, true);
    __syncthreads();

    init_acc(acc, b3, wn, lc);
    for (int s = 0; s < 4; ++s) {
        if (s < 3) stage_B(B_lds[(s + 1) & 1], W3p + (size_t)(s + 1) * 8192, wave, lane);
        compute_step(A_lds, B_lds[s & 1], s, wm, wn, lane, acc);
        if (s < 3) __syncthreads();
    }

    {
        float s_[2][4], q_[2][4];
#pragma unroll
        for (int mf = 0; mf < 2; ++mf)
#pragma unroll
            for (int r = 0; r < 4; ++r) {
                float s = 0.f, qq = 0.f;
#pragma unroll
                for (int nf = 0; nf < 4; ++nf) {
                    const float v = acc[mf][nf][r];
                    s += v; qq += v * v;
                }
                s_[mf][r] = s; q_[mf][r] = qq;
            }
#pragma unroll
        for (int m = 1; m < 16; m <<= 1)
#pragma unroll
            for (int mf = 0; mf < 2; ++mf)
#pragma unroll
                for (int r = 0; r < 4; ++r) {
                    s_[mf][r] += __shfl_xor(s_[mf][r], m, 64);
                    q_[mf][r] += __shfl_xor(q_[mf][r], m, 64);
                }
        if (lc == 0) {
#pragma unroll
            for (int mf = 0; mf < 2; ++mf)
#pragma unroll
                for (int r = 0; r < 4; ++r) {
                    const int row = wm * 32 + mf * 16 + lq * 4 + r;
                    red[wn][row][0] = s_[mf][r];
                    red[wn][row][1] = q_[mf][r];
                }
        }
    }
    __syncthreads();

    float mu[2][4], rs[2][4];
#pragma unroll
    for (int mf = 0; mf < 2; ++mf)
#pragma unroll
        for (int r = 0; r < 4; ++r) {
            const int row = wm * 32 + mf * 16 + lq * 4 + r;
            const float S = red[0][row][0] + red[1][row][0];
            const float Q = red[0][row][1] + red[1][row][1];
            const float m_ = S * (1.0f / 128.0f);
            mu[mf][r] = m_;
            rs[mf][r] = rsqrtf(Q * (1.0f / 128.0f) - m_ * m_ + LN_EPS);
        }

#pragma unroll
    for (int nf = 0; nf < 4; ++nf) {
        const int col = wn * 64 + nf * 16 + lc;
        const float gc = g[col], bc = bt[col];
#pragma unroll
        for (int mf = 0; mf < 2; ++mf)
#pragma unroll
            for (int r = 0; r < 4; ++r) {
                const int row = wm * 32 + mf * 16 + lq * 4 + r;
                const int v = v0 + row;
                if (v < N_NODES) {
                    float o = (acc[mf][nf][r] - mu[mf][r]) * rs[mf][r] * gc + bc;
                    o += x[(size_t)v * DIM + col];
                    out_x[(size_t)v * DIM + col] = o;
                }
            }
    }
}

extern "C" void kernel_launch(void* const* d_in, const int* in_sizes, int n_in,
                              void* d_out, int out_size, void* d_ws, size_t ws_size,
                              hipStream_t stream) {
    const float* x   = (const float*)d_in[0];
    const int*   ei  = (const int*)d_in[1];
    const float* ea  = (const float*)d_in[2];
    const float* ew1 = (const float*)d_in[3];
    const float* eb1 = (const float*)d_in[4];
    const float* ew2 = (const float*)d_in[5];
    const float* eb2 = (const float*)d_in[6];
    const float* ew3 = (const float*)d_in[7];
    const float* eb3 = (const float*)d_in[8];
    const float* eg  = (const float*)d_in[9];
    const float* ebt = (const float*)d_in[10];
    const float* nw1 = (const float*)d_in[11];
    const float* nb1 = (const float*)d_in[12];
    const float* nw2 = (const float*)d_in[13];
    const float* nb2 = (const float*)d_in[14];
    const float* nw3 = (const float*)d_in[15];
    const float* nb3 = (const float*)d_in[16];
    const float* ng  = (const float*)d_in[17];
    const float* nbt = (const float*)d_in[18];

    float* out_x = (float*)d_out;                   // [N_NODES,128]
    float* out_e = out_x + (size_t)N_NODES * DIM;   // [N_EDGES,128]

    char* ws = (char*)d_ws;
    float* agg = (float*)ws;                        // 25,600,000 B
    size_t o = 25600000;
    unsigned short* eW1p = (unsigned short*)(ws + o); o += 12 * 16384;
    unsigned short* eW2p = (unsigned short*)(ws + o); o += 4 * 16384;
    unsigned short* eW3p = (unsigned short*)(ws + o); o += 4 * 16384;
    unsigned short* nW1p = (unsigned short*)(ws + o); o += 8 * 16384;
    unsigned short* nW2p = (unsigned short*)(ws + o); o += 4 * 16384;
    unsigned short* nW3p = (unsigned short*)(ws + o); o += 4 * 16384;

    prep_w<<<12, 256, 0, stream>>>(ew1, eW1p);
    prep_w<<< 4, 256, 0, stream>>>(ew2, eW2p);
    prep_w<<< 4, 256, 0, stream>>>(ew3, eW3p);
    prep_w<<< 8, 256, 0, stream>>>(nw1, nW1p);
    prep_w<<< 4, 256, 0, stream>>>(nw2, nW2p);
    prep_w<<< 4, 256, 0, stream>>>(nw3, nW3p);

    hipMemsetAsync(agg, 0, (size_t)N_NODES * DIM * sizeof(float), stream);

    edge_mfma<<<N_EDGES / 64, 256, 0, stream>>>(
        x, ei, ea, eW1p, eb1, eW2p, eb2, eW3p, eb3, eg, ebt, out_e, agg);

    node_mfma<<<(N_NODES + 63) / 64, 256, 0, stream>>>(
        x, agg, nW1p, nb1, nW2p, nb2, nW3p, nb3, ng, nbt, out_x);
}